// Round 6
// baseline (85.099 us; speedup 1.0000x reference)
//
#include <hip/hip_runtime.h>
#include <hip/hip_bf16.h>
#include <math.h>

// Problem constants
#define BB   2
#define NN   2048
#define DIMM 512
#define HH   8
#define NC3  1536
#define BN   4096

typedef __attribute__((ext_vector_type(8))) short short8;
typedef __attribute__((ext_vector_type(4))) float f32x4;
typedef unsigned short u16t;

__device__ inline short bfc(float f) {
    __hip_bfloat16 h = __float2bfloat16(f);
    return *reinterpret_cast<short*>(&h);
}
__device__ inline float bf2f(u16t u) {
    return __uint_as_float(((unsigned)u) << 16);
}

// XOR-swizzle of 16B granules within [rows x 64B] LDS tiles (involution).
// Applied as: linear LDS dest + pre-swizzled GLOBAL source (global_load_lds),
// swizzled ds_read offsets. LDS[L] = g[SWZ(L)] => read SWZ(P) yields g[P].
#define SWZ(P) ((P) ^ ((((P) >> 7) & 3) << 4))

// global -> LDS direct DMA, 16B per lane. LDS dest = uniform base + lane*16.
__device__ inline void gll16(const u16t* gp, void* lp) {
    __builtin_amdgcn_global_load_lds(
        (const __attribute__((address_space(1))) void*)gp,
        (__attribute__((address_space(3))) void*)lp,
        16, 0, 0);
}

// ---------------------------------------------------------------------------
// fp32 -> bf16: x = 524288 float4, w_qkv = 196608 float4. grid 2816 x 256.
// (R4/R5 bug was here: counts were halved, leaving half of xb/wqb unwritten.)
// ---------------------------------------------------------------------------
__global__ __launch_bounds__(256) void cvt_bf16(
    const float* __restrict__ x, const float* __restrict__ wq,
    u16t* __restrict__ xb, u16t* __restrict__ wqb)
{
    int t = blockIdx.x * 256 + threadIdx.x;
    const float4* src; ushort4* dst; int i;
    if (t < 524288) { src = (const float4*)x;  dst = (ushort4*)xb;  i = t; }
    else            { src = (const float4*)wq; dst = (ushort4*)wqb; i = t - 524288; }
    float4 v = src[i];
    ushort4 u;
    u.x = (u16t)bfc(v.x); u.y = (u16t)bfc(v.y);
    u.z = (u16t)bfc(v.z); u.w = (u16t)bfc(v.w);
    dst[i] = u;
}

// ---------------------------------------------------------------------------
// qkv GEMM: QKV[4096 x 1536](bf16) = xb[4096 x 512] @ wqb[1536 x 512]^T
// 128x128 tile, BK=32, 4 waves (2x2, wave-tile 64x64).
// global_load_lds staging (pre-swizzled source), LDS double-buffer,
// ONE barrier per K-step (T3 minimum-2-phase).
// ---------------------------------------------------------------------------
__global__ __launch_bounds__(256) void qkvgemm(
    const u16t* __restrict__ A, const u16t* __restrict__ Bw,
    u16t* __restrict__ QKV)
{
    __shared__ __align__(16) char smem[32768];   // buf: 16KB = A 8KB + B 8KB

    const int tid  = threadIdx.x;
    const int wave = tid >> 6, lane = tid & 63;
    const int wr = wave >> 1, wc = wave & 1;

    // XCD-aware bijective swizzle: nwg = 384, 384/8 = 48
    int bid = blockIdx.y * gridDim.x + blockIdx.x;
    int swz = (bid & 7) * 48 + (bid >> 3);
    const int row0 = (swz & 31) * 128;          // gridDim.x == 32
    const int c0   = (swz >> 5) * 128;

    // staging: 8 A-chunks + 8 B-chunks of 1KB; wave w owns A{2w,2w+1}, B{2w,2w+1}
    size_t gA[2], gB[2];
#pragma unroll
    for (int j = 0; j < 2; ++j) {
        int c = wave * 2 + j;
        int X = (c * 64 + lane) * 16;           // linear LDS byte offset
        int gi = SWZ(X) >> 4;                   // source granule index
        int row = gi >> 2, col = (gi & 3) * 8;
        gA[j] = (size_t)(row0 + row) * DIMM + col;
        gB[j] = (size_t)(c0   + row) * DIMM + col;
    }

    // per-lane swizzled read offsets (loop-invariant)
    int rdA[4], rdB[4];
#pragma unroll
    for (int i = 0; i < 4; ++i) {
        int Pa = (wr * 64 + i * 16 + (lane & 15)) * 64 + (lane >> 4) * 16;
        rdA[i] = SWZ(Pa);
        int Pb = (wc * 64 + i * 16 + (lane & 15)) * 64 + (lane >> 4) * 16;
        rdB[i] = 8192 + SWZ(Pb);
    }

#define QSTAGE(BUF, KT) {                                                     \
    char* sb = smem + (BUF) * 16384;                                          \
    _Pragma("unroll")                                                         \
    for (int j = 0; j < 2; ++j) {                                             \
        gll16(A  + gA[j] + (KT), sb + (wave * 2 + j) * 1024);                 \
        gll16(Bw + gB[j] + (KT), sb + 8192 + (wave * 2 + j) * 1024);          \
    } }

    f32x4 acc[4][4];
#pragma unroll
    for (int i = 0; i < 4; ++i)
#pragma unroll
        for (int j = 0; j < 4; ++j) acc[i][j] = (f32x4){0.f, 0.f, 0.f, 0.f};

    QSTAGE(0, 0);
    for (int t = 0; t < 16; ++t) {
        __syncthreads();                      // drains STAGE(t), fences reads(t-1)
        if (t < 15) QSTAGE((t + 1) & 1, (t + 1) * 32);
        const char* rb = smem + (t & 1) * 16384;
        short8 af[4], bfr[4];
#pragma unroll
        for (int i = 0; i < 4; ++i) {
            af[i]  = *(const short8*)(rb + rdA[i]);
            bfr[i] = *(const short8*)(rb + rdB[i]);
        }
#pragma unroll
        for (int i = 0; i < 4; ++i)
#pragma unroll
            for (int j = 0; j < 4; ++j)
                acc[i][j] = __builtin_amdgcn_mfma_f32_16x16x32_bf16(
                    af[i], bfr[j], acc[i][j], 0, 0, 0);
    }
#undef QSTAGE

    // epilogue: bf16 row-major. C/D: col = lane&15, row = (lane>>4)*4 + reg
#pragma unroll
    for (int j = 0; j < 4; ++j) {
        int col = c0 + wc * 64 + j * 16 + (lane & 15);
#pragma unroll
        for (int i = 0; i < 4; ++i) {
#pragma unroll
            for (int r = 0; r < 4; ++r) {
                int row = row0 + wr * 64 + i * 16 + (lane >> 4) * 4 + r;
                QKV[(size_t)row * NC3 + col] = (u16t)bfc(acc[i][j][r]);
            }
        }
    }
}

// ---------------------------------------------------------------------------
// Mpart (proven): per (bh, chunk of 128 rows)
// ---------------------------------------------------------------------------
__global__ __launch_bounds__(256) void mpart(
    const u16t* __restrict__ QKV, float* __restrict__ Mp, float* __restrict__ ksump)
{
    __shared__ float qs[128][64];
    __shared__ float ks[128][64];

    int bh = blockIdx.x, ch = blockIdx.y;
    int b = bh >> 3, h = bh & 7;
    int tid = threadIdx.x, w = tid >> 6, lane = tid & 63;
    const u16t* Qb = QKV + ((size_t)b * NN + ch * 128) * NC3 + h * 64;
    const u16t* Kb = Qb + 512;

    for (int rr = 0; rr < 32; ++rr) {
        int r = w * 32 + rr;
        float qv = bf2f(Qb[(size_t)r * NC3 + lane]);
        float m = qv;
#pragma unroll
        for (int off = 32; off; off >>= 1) m = fmaxf(m, __shfl_xor(m, off));
        float e = __expf(qv - m);
        float s = e;
#pragma unroll
        for (int off = 32; off; off >>= 1) s += __shfl_xor(s, off);
        qs[r][lane] = e / s;
        ks[r][lane] = __expf(bf2f(Kb[(size_t)r * NC3 + lane]));
    }
    __syncthreads();

    int tx = tid & 15, ty = tid >> 4;
    float acc[4][4];
#pragma unroll
    for (int i = 0; i < 4; ++i)
#pragma unroll
        for (int j = 0; j < 4; ++j) acc[i][j] = 0.f;

#pragma unroll 8
    for (int r = 0; r < 128; ++r) {
        float4 a = *(const float4*)&ks[r][ty * 4];
        float4 b2 = *(const float4*)&qs[r][tx * 4];
        acc[0][0] += a.x * b2.x; acc[0][1] += a.x * b2.y;
        acc[0][2] += a.x * b2.z; acc[0][3] += a.x * b2.w;
        acc[1][0] += a.y * b2.x; acc[1][1] += a.y * b2.y;
        acc[1][2] += a.y * b2.z; acc[1][3] += a.y * b2.w;
        acc[2][0] += a.z * b2.x; acc[2][1] += a.z * b2.y;
        acc[2][2] += a.z * b2.z; acc[2][3] += a.z * b2.w;
        acc[3][0] += a.w * b2.x; acc[3][1] += a.w * b2.y;
        acc[3][2] += a.w * b2.z; acc[3][3] += a.w * b2.w;
    }

    float* mp = Mp + ((size_t)(bh * 16 + ch)) * 4096;
#pragma unroll
    for (int i = 0; i < 4; ++i)
        *(float4*)(mp + (ty * 4 + i) * 64 + tx * 4) =
            make_float4(acc[i][0], acc[i][1], acc[i][2], acc[i][3]);

    if (tid < 64) {
        float s = 0.f;
        for (int r = 0; r < 128; ++r) s += ks[r][tid];
        ksump[(bh * 16 + ch) * 64 + tid] = s;
    }
}

// ---------------------------------------------------------------------------
// mfinal (proven): reduce Mp -> M, fold into w_out -> W2T (bf16)
// ---------------------------------------------------------------------------
__global__ __launch_bounds__(256) void mfinal(
    const float* __restrict__ Mp, const float* __restrict__ ksump,
    const float* __restrict__ w_out, u16t* __restrict__ W2T)
{
    __shared__ float kst[64];
    __shared__ float Ms[64][68];
    __shared__ float Wt[64][64];

    int bh = blockIdx.x, ot = blockIdx.y;
    int b = bh >> 3, h = bh & 7;
    int tid = threadIdx.x;
    int d = tid & 63, og = tid >> 6;

    if (tid < 64) {
        float s = 0.f;
        for (int c = 0; c < 16; ++c) s += ksump[(bh * 16 + c) * 64 + tid];
        kst[tid] = s;
    }
    __syncthreads();

    for (int idx = tid; idx < 4096; idx += 256) {
        float s = 0.f;
        for (int c = 0; c < 16; ++c)
            s += Mp[((size_t)(bh * 16 + c)) * 4096 + idx];
        Ms[idx >> 6][idx & 63] = s / kst[idx >> 6];
    }
    __syncthreads();

    float Mreg[64];
#pragma unroll
    for (int e4 = 0; e4 < 16; ++e4) {
        float4 v = *(const float4*)&Ms[d][e4 * 4];
        Mreg[e4 * 4 + 0] = v.x; Mreg[e4 * 4 + 1] = v.y;
        Mreg[e4 * 4 + 2] = v.z; Mreg[e4 * 4 + 3] = v.w;
    }

    for (int sub = 0; sub < 2; ++sub) {
        int ob = ot * 128 + sub * 64;
        __syncthreads();
        {
            int o = tid >> 2, e0 = (tid & 3) * 16;
#pragma unroll
            for (int q = 0; q < 4; ++q)
                *(float4*)&Wt[o][e0 + q * 4] =
                    *(const float4*)&w_out[(size_t)(ob + o) * DIMM + h * 64 + e0 + q * 4];
        }
        __syncthreads();
#pragma unroll
        for (int oo = 0; oo < 16; ++oo) {
            int o = og * 16 + oo;
            float a = 0.f;
#pragma unroll
            for (int e4 = 0; e4 < 16; ++e4) {
                float4 wv = *(const float4*)&Wt[o][e4 * 4];
                a += wv.x * Mreg[e4 * 4 + 0] + wv.y * Mreg[e4 * 4 + 1]
                   + wv.z * Mreg[e4 * 4 + 2] + wv.w * Mreg[e4 * 4 + 3];
            }
            W2T[((size_t)b * DIMM + ob + o) * DIMM + h * 64 + d] = (u16t)bfc(a);
        }
    }
}

// ---------------------------------------------------------------------------
// out GEMM: Out[4096 x 512](f32) = V[4096 x 512](bf16, stride 1536)
//           @ W2T_b[512 x 512]^T(bf16) + bias
// 128x64 tile, BK=32, 4 waves (2x2, wave-tile 64x32). GLL + dbuf + 1 barrier.
// ---------------------------------------------------------------------------
__global__ __launch_bounds__(256) void outgemm(
    const u16t* __restrict__ Aq, const u16t* __restrict__ W2T,
    const float* __restrict__ bias, float* __restrict__ Out)
{
    __shared__ __align__(16) char smem[24576];   // buf: 12KB = A 8KB + B 4KB

    const int tid  = threadIdx.x;
    const int wave = tid >> 6, lane = tid & 63;
    const int wr = wave >> 1, wc = wave & 1;

    int bid = blockIdx.y * gridDim.x + blockIdx.x;   // 32x8 = 256
    int swz = (bid & 7) * 32 + (bid >> 3);
    const int row0 = (swz & 31) * 128;
    const int c0   = (swz >> 5) * 64;
    const u16t* Bp = W2T + (size_t)(row0 >> 11) * (DIMM * DIMM);

    // chunks: A 8 (wave: 2w,2w+1), B 4 (wave: w)
    size_t gA[2], gB;
#pragma unroll
    for (int j = 0; j < 2; ++j) {
        int c = wave * 2 + j;
        int gi = SWZ((c * 64 + lane) * 16) >> 4;
        int row = gi >> 2, col = (gi & 3) * 8;
        gA[j] = (size_t)(row0 + row) * NC3 + col;
    }
    {
        int gi = SWZ((wave * 64 + lane) * 16) >> 4;
        int row = gi >> 2, col = (gi & 3) * 8;
        gB = (size_t)(c0 + row) * DIMM + col;
    }

    int rdA[4], rdB[2];
#pragma unroll
    for (int i = 0; i < 4; ++i) {
        int Pa = (wr * 64 + i * 16 + (lane & 15)) * 64 + (lane >> 4) * 16;
        rdA[i] = SWZ(Pa);
    }
#pragma unroll
    for (int j = 0; j < 2; ++j) {
        int Pb = (wc * 32 + j * 16 + (lane & 15)) * 64 + (lane >> 4) * 16;
        rdB[j] = 8192 + SWZ(Pb);
    }

#define OSTAGE(BUF, KT) {                                                     \
    char* sb = smem + (BUF) * 12288;                                          \
    _Pragma("unroll")                                                         \
    for (int j = 0; j < 2; ++j)                                               \
        gll16(Aq + gA[j] + (KT), sb + (wave * 2 + j) * 1024);                 \
    gll16(Bp + gB + (KT), sb + 8192 + wave * 1024);                           \
    }

    f32x4 acc[4][2];
#pragma unroll
    for (int i = 0; i < 4; ++i)
#pragma unroll
        for (int j = 0; j < 2; ++j) acc[i][j] = (f32x4){0.f, 0.f, 0.f, 0.f};

    OSTAGE(0, 0);
    for (int t = 0; t < 16; ++t) {
        __syncthreads();
        if (t < 15) OSTAGE((t + 1) & 1, (t + 1) * 32);
        const char* rb = smem + (t & 1) * 12288;
        short8 af[4], bfr[2];
#pragma unroll
        for (int i = 0; i < 4; ++i) af[i]  = *(const short8*)(rb + rdA[i]);
#pragma unroll
        for (int j = 0; j < 2; ++j) bfr[j] = *(const short8*)(rb + rdB[j]);
#pragma unroll
        for (int i = 0; i < 4; ++i)
#pragma unroll
            for (int j = 0; j < 2; ++j)
                acc[i][j] = __builtin_amdgcn_mfma_f32_16x16x32_bf16(
                    af[i], bfr[j], acc[i][j], 0, 0, 0);
    }
#undef OSTAGE

#pragma unroll
    for (int j = 0; j < 2; ++j) {
        int col = c0 + wc * 32 + j * 16 + (lane & 15);
        float bb = bias[col];
#pragma unroll
        for (int i = 0; i < 4; ++i) {
#pragma unroll
            for (int r = 0; r < 4; ++r) {
                int row = row0 + wr * 64 + i * 16 + (lane >> 4) * 4 + r;
                Out[(size_t)row * DIMM + col] = acc[i][j][r] + bb;
            }
        }
    }
}

// ---------------------------------------------------------------------------
extern "C" void kernel_launch(void* const* d_in, const int* in_sizes, int n_in,
                              void* d_out, int out_size, void* d_ws, size_t ws_size,
                              hipStream_t stream)
{
    const float* x     = (const float*)d_in[0];   // (2,2048,512)
    const float* w_qkv = (const float*)d_in[1];   // (1536,512)
    const float* w_out = (const float*)d_in[2];   // (512,512)
    const float* b_out = (const float*)d_in[3];   // (512,)
    float* out = (float*)d_out;                   // (2,2048,512)

    char* w = (char*)d_ws;
    u16t*  xb   = (u16t*) (w);              //  4,194,304 B
    u16t*  wqb  = (u16t*) (w + 4194304);    //  1,572,864 B
    u16t*  QKV  = (u16t*) (w + 5767168);    // 12,582,912 B
    float* Mp   = (float*)(w + 18350080);   //  4,194,304 B
    float* ksum = (float*)(w + 22544384);   //     65,536 B
    u16t*  W2T  = (u16t*) (w + 22609920);   //  1,048,576 B  (end ~23.7 MB)

    // 1) fp32 -> bf16 for GEMM inputs (FIXED counts: 524288 + 196608 float4)
    cvt_bf16<<<dim3(2816), 256, 0, stream>>>(x, w_qkv, xb, wqb);

    // 2) qkv projection -> unified bf16 QKV [4096][1536]
    qkvgemm<<<dim3(32, 12), 256, 0, stream>>>(xb, wqb, QKV);

    // 3) partial M + partial k-softmax denominator
    mpart<<<dim3(BB * HH, 16), 256, 0, stream>>>(QKV, Mp, ksum);

    // 4) reduce partials + fold M into w_out -> W2T (bf16)
    mfinal<<<dim3(BB * HH, 4), 256, 0, stream>>>(Mp, ksum, w_out, W2T);

    // 5) out = V @ W2T^T + bias
    outgemm<<<dim3(32, 8), 256, 0, stream>>>(QKV + 1024, W2T, b_out, out);
}